// Round 7
// baseline (1059.288 us; speedup 1.0000x reference)
//
#include <hip/hip_runtime.h>
#include <math.h>

// Contraction index k' = c*8 + i (c-major) so B-matrix [uo][k'] is W's native
// [c][u][o][i] layout elementwise-scaled.  Single persistent kernel, 5 hand-rolled
// device-scope barriers replace 5 dispatch boundaries (~8.7 us each measured).
#define B_ 512
#define C_ 1152
#define U_ 10
#define O_ 16
#define I_ 8
#define K_ 9216
#define UO_ 160
#define NBLK 512
#define NTHR 256

typedef short bf16x8 __attribute__((ext_vector_type(8)));
typedef float f32x4 __attribute__((ext_vector_type(4)));
typedef unsigned short u16x8v __attribute__((ext_vector_type(8)));

// ---- persistent device scratch (fully overwritten every call) ----
__device__ __attribute__((aligned(16))) unsigned short g_xb2[B_*K_];  // bf16 x [b][k']
__device__ __attribute__((aligned(16))) unsigned short g_xT2[K_*B_];  // bf16 x^T [k'][b]
__device__ __attribute__((aligned(16))) unsigned short g_Wc[C_*1280]; // bf16 cw-scaled W (native layout)
__device__ __attribute__((aligned(16))) unsigned short g_vT[UO_*B_];  // bf16 v^T [uo][b]
__device__ float g_b[C_*U_];                                          // routing logits [c][u]
__device__ unsigned g_cnt;                                            // barrier arrivals
__device__ unsigned g_gen;                                            // barrier generation (monotonic)

union ShMem {
    unsigned short prep_lds[32*256];                 // 16 KB
    float red[4][16][32];                            // 8 KB
    struct { float agg[2][U_]; float cws[2][U_]; } tb;
};

__device__ __forceinline__ unsigned short f2bf(float f) {
    unsigned u = __builtin_bit_cast(unsigned, f);
    unsigned r = (u + 0x7FFFu + ((u >> 16) & 1u)) >> 16;
    return (unsigned short)r;
}

// ---- grid barrier: sense-reversing, device-scope, bounded spin ----
__device__ __forceinline__ void gbar() {
    __syncthreads();                 // all waves drain their stores (s_waitcnt 0 + s_barrier)
    if (threadIdx.x == 0) {
        __threadfence();             // agent-scope release: L2 writeback visible at L3
        unsigned mygen = __hip_atomic_load(&g_gen, __ATOMIC_RELAXED, __HIP_MEMORY_SCOPE_AGENT);
        unsigned old = __hip_atomic_fetch_add(&g_cnt, 1u, __ATOMIC_ACQ_REL, __HIP_MEMORY_SCOPE_AGENT);
        if (old == NBLK - 1u) {
            __hip_atomic_store(&g_cnt, 0u, __ATOMIC_RELAXED, __HIP_MEMORY_SCOPE_AGENT);
            __hip_atomic_fetch_add(&g_gen, 1u, __ATOMIC_RELEASE, __HIP_MEMORY_SCOPE_AGENT);
        } else {
            long spins = 0;
            while (__hip_atomic_load(&g_gen, __ATOMIC_ACQUIRE, __HIP_MEMORY_SCOPE_AGENT) == mygen) {
                __builtin_amdgcn_s_sleep(2);
                if (++spins > (1L << 23)) break;    // failsafe: fail fast, never hang
            }
        }
        __threadfence();             // agent-scope acquire: invalidate stale L1/L2
    }
    __syncthreads();
}

// ---- phase: prep. 756 tasks: 576 x-tiles (xb2 + xT2) and 180 W-convert (Wc=0.1*W) ----
__device__ void ph_prep(const float* __restrict__ x, const float* __restrict__ W,
                        int bid, int tid, ShMem& sh) {
    int li = tid >> 5, lc = tid & 31;
    for (int task = bid; task < 756; task += NBLK) {
        if (task < 576) {
            int b0 = (task & 15) * 32;
            int c0 = (task >> 4) * 32;
            for (int rep = 0; rep < 32; rep++) {
                float v = x[(b0+rep)*K_ + li*1152 + c0 + lc];
                sh.prep_lds[rep*256 + ((lc*8+li) ^ ((rep&31)<<3))] = f2bf(v);
            }
            __syncthreads();
            {   // xb2: 32 contiguous elems per thread
                int b = tid >> 3, part = tid & 7;
                int swz = (b&31) << 3;
                const u16x8v* lv = (const u16x8v*)sh.prep_lds;
                u16x8v* ov = (u16x8v*)(g_xb2 + (b0+b)*K_ + c0*8 + part*32);
                #pragma unroll
                for (int g = 0; g < 4; g++)
                    ov[g] = lv[(b*256 + ((part*32 + g*8) ^ swz)) >> 3];
            }
            for (int p = 0; p < 8; p++) {   // xT2: 8 threads per k'-row
                int r = p*32 + (tid>>3);
                int bp = (tid&7)*4;
                ushort4 o;
                unsigned short* po = (unsigned short*)&o;
                #pragma unroll
                for (int q = 0; q < 4; q++) {
                    int b = bp + q;
                    po[q] = sh.prep_lds[b*256 + (r ^ ((b&31)<<3))];
                }
                *(ushort4*)(g_xT2 + (c0*8 + r)*B_ + b0 + bp) = o;
            }
            __syncthreads();                // protect lds before next task
        } else {
            int base = (task - 576) * 8192;
            for (int j = 0; j < 8; j++) {
                float4 v = *(const float4*)(W + base + j*1024 + tid*4);
                ushort4 o;
                o.x = f2bf(0.1f*v.x); o.y = f2bf(0.1f*v.y);
                o.z = f2bf(0.1f*v.z); o.w = f2bf(0.1f*v.w);
                *(ushort4*)(g_Wc + base + j*1024 + tid*4) = o;
            }
        }
    }
}

// ---- phase: S = x @ Wc^T fused with squash -> vT (+ final out). 160 tasks. ----
__device__ void ph_s(float* __restrict__ out, int write_out, int bid, int tid, ShMem& sh) {
    if (bid < 160) {
        int lane = tid & 63, w = tid >> 6;
        int mt = bid & 31, nt = bid >> 5;
        int m0 = mt*16, n0 = nt*32;
        int ra = lane & 15, kq = (lane>>4)*8;
        const unsigned short* pa  = g_xb2 + (m0+ra)*K_ + w*2304 + kq;
        const unsigned short* pb0 = g_Wc + (w*288 + (kq>>3))*1280 + (n0+ra)*8;
        const unsigned short* pb1 = pb0 + 128;
        f32x4 acc0 = {0.f,0.f,0.f,0.f};
        f32x4 acc1 = {0.f,0.f,0.f,0.f};
        #pragma unroll 6
        for (int s = 0; s < 72; s++) {          // K/wave = 2304
            bf16x8 a  = *(const bf16x8*)pa;
            bf16x8 b0 = *(const bf16x8*)pb0;
            bf16x8 b1 = *(const bf16x8*)pb1;
            acc0 = __builtin_amdgcn_mfma_f32_16x16x32_bf16(a, b0, acc0, 0, 0, 0);
            acc1 = __builtin_amdgcn_mfma_f32_16x16x32_bf16(a, b1, acc1, 0, 0, 0);
            pa += 32; pb0 += 5120; pb1 += 5120; // +4 channels
        }
        int row = (lane>>4)*4, col = lane & 15;
        #pragma unroll
        for (int r = 0; r < 4; r++) {
            sh.red[w][row+r][col]    = acc0[r];
            sh.red[w][row+r][col+16] = acc1[r];
        }
        __syncthreads();
        int g = tid >> 3, brow = g & 15, uh = g >> 4, o = (tid & 7)*2;
        int cA = uh*16 + o, cB = cA + 1;
        float t0 = sh.red[0][brow][cA] + sh.red[1][brow][cA] + sh.red[2][brow][cA] + sh.red[3][brow][cA];
        float t1 = sh.red[0][brow][cB] + sh.red[1][brow][cB] + sh.red[2][brow][cB] + sh.red[3][brow][cB];
        float nrm = t0*t0 + t1*t1;
        nrm += __shfl_xor(nrm, 1);
        nrm += __shfl_xor(nrm, 2);
        nrm += __shfl_xor(nrm, 4);
        float f = nrm / ((1.f + nrm) * sqrtf(nrm));
        float v0 = t0*f, v1 = t1*f;
        int ug = nt*2 + uh, bg = m0 + brow;
        g_vT[(ug*16+o)*B_ + bg]   = f2bf(v0);
        g_vT[(ug*16+o+1)*B_ + bg] = f2bf(v1);
        if (write_out) {
            float2 o2; o2.x = v0; o2.y = v1;
            *(float2*)(out + (bg*10 + ug)*16 + o) = o2;
        }
        __syncthreads();                        // sh.red safe before next phase
    }
}

// ---- phase: TB. T' in regs + agree + b-update + softmax + next Wc. 576 tasks. ----
__device__ void ph_tb(const float* __restrict__ W, int first, int bid, int tid, ShMem& sh) {
    int lane = tid & 63, w = tid >> 6;
    for (int task = bid; task < 576; task += NBLK) {
        int c0 = task * 2;
        int ra = lane & 15, kq = (lane>>4)*8;
        int ct = lane >> 5;
        int i0 = ((lane>>4) & 1) * 4;
        int o  = lane & 15;
        const unsigned short* pa0 = g_xT2 + (c0*8 + ra)*B_ + kq;
        for (int nt = w; nt < 5; nt += 4) {     // wave 0 also covers tile 4
            int n0 = nt*32;
            const unsigned short* pa  = pa0;
            const unsigned short* pb0 = g_vT + (n0+ra)*B_ + kq;
            const unsigned short* pb1 = pb0 + 16*B_;
            f32x4 acc0 = {0.f,0.f,0.f,0.f};
            f32x4 acc1 = {0.f,0.f,0.f,0.f};
            #pragma unroll 4
            for (int s = 0; s < 16; s++) {      // K = 512
                bf16x8 a  = *(const bf16x8*)pa;
                bf16x8 b0 = *(const bf16x8*)pb0;
                bf16x8 b1 = *(const bf16x8*)pb1;
                acc0 = __builtin_amdgcn_mfma_f32_16x16x32_bf16(a, b0, acc0, 0, 0, 0);
                acc1 = __builtin_amdgcn_mfma_f32_16x16x32_bf16(a, b1, acc1, 0, 0, 0);
                pa += 32; pb0 += 32; pb1 += 32;
            }
            const float* wr = W + (c0+ct)*1280;
            float4 wa = *(const float4*)(wr + (2*nt  )*128 + o*8 + i0);
            float4 wb = *(const float4*)(wr + (2*nt+1)*128 + o*8 + i0);
            float p0 = wa.x*acc0[0] + wa.y*acc0[1] + wa.z*acc0[2] + wa.w*acc0[3];
            float p1 = wb.x*acc1[0] + wb.y*acc1[1] + wb.z*acc1[2] + wb.w*acc1[3];
            #pragma unroll
            for (int m = 1; m < 32; m <<= 1) {
                p0 += __shfl_xor(p0, m);
                p1 += __shfl_xor(p1, m);
            }
            if ((lane & 31) == 0) {
                sh.tb.agg[ct][2*nt]   = p0 * (1.f/512.f);
                sh.tb.agg[ct][2*nt+1] = p1 * (1.f/512.f);
            }
        }
        __syncthreads();
        if (tid < 2) {                          // per-channel b-update + softmax
            int c = c0 + tid;
            float bv[U_];
            float mx = -3e38f;
            #pragma unroll
            for (int u = 0; u < U_; u++) {
                float v = sh.tb.agg[tid][u];
                if (!first) v += g_b[c*U_ + u];
                g_b[c*U_ + u] = v;
                bv[u] = v;
                mx = fmaxf(mx, v);
            }
            float sm = 0.f;
            #pragma unroll
            for (int u = 0; u < U_; u++) { bv[u] = expf(bv[u] - mx); sm += bv[u]; }
            float inv = 1.f/sm;
            #pragma unroll
            for (int u = 0; u < U_; u++) sh.tb.cws[tid][u] = bv[u]*inv;
        }
        __syncthreads();
        for (int e = tid*8; e < 2560; e += NTHR*8) {   // next-iter Wc for both channels
            int ch  = (e >= 1280) ? 1 : 0;
            int off = e - ch*1280;
            int u   = off >> 7;
            float s = sh.tb.cws[ch][u];
            const float* wp = W + (c0+ch)*1280 + off;
            float4 a4 = *(const float4*)wp;
            float4 b4 = *(const float4*)(wp + 4);
            u16x8v ov;
            ov[0] = f2bf(a4.x*s); ov[1] = f2bf(a4.y*s); ov[2] = f2bf(a4.z*s); ov[3] = f2bf(a4.w*s);
            ov[4] = f2bf(b4.x*s); ov[5] = f2bf(b4.y*s); ov[6] = f2bf(b4.z*s); ov[7] = f2bf(b4.w*s);
            *(u16x8v*)(g_Wc + (c0+ch)*1280 + off) = ov;
        }
        __syncthreads();                        // sh.tb safe before next task/phase
    }
}

// ---- the single persistent kernel ----
__global__ __launch_bounds__(NTHR, 2) void k_all(const float* __restrict__ x,
                                                 const float* __restrict__ W,
                                                 float* __restrict__ out) {
    __shared__ ShMem sh;
    int bid = blockIdx.x, tid = threadIdx.x;
    ph_prep(x, W, bid, tid, sh);
    gbar();
    ph_s(out, 0, bid, tid, sh);     // t=0 (Wc = 0.1*W)
    gbar();
    ph_tb(W, 1, bid, tid, sh);
    gbar();
    ph_s(out, 0, bid, tid, sh);     // t=1
    gbar();
    ph_tb(W, 0, bid, tid, sh);
    gbar();
    ph_s(out, 1, bid, tid, sh);     // t=2, writes final output
}

extern "C" void kernel_launch(void* const* d_in, const int* in_sizes, int n_in,
                              void* d_out, int out_size, void* d_ws, size_t ws_size,
                              hipStream_t stream) {
    const float* x = (const float*)d_in[0];
    const float* W = (const float*)d_in[1];
    float* out = (float*)d_out;
    k_all<<<dim3(NBLK), dim3(NTHR), 0, stream>>>(x, W, out);
}

// Round 8
// 247.853 us; speedup vs baseline: 4.2739x; 4.2739x over previous
//
#include <hip/hip_runtime.h>
#include <math.h>

// Contraction index k' = c*8 + i (c-major) so B-matrix [uo][k'] is W's native
// [c][u][o][i] layout elementwise-scaled.  Single persistent kernel; 5 grid-wide
// syncs via a contention-free flag barrier (per-block arrive slots + block-0 poll
// + generation broadcast; RELAXED spins, single acquire fence on exit).
#define B_ 512
#define C_ 1152
#define U_ 10
#define O_ 16
#define I_ 8
#define K_ 9216
#define UO_ 160
#define NBLK 512
#define NTHR 256

typedef short bf16x8 __attribute__((ext_vector_type(8)));
typedef float f32x4 __attribute__((ext_vector_type(4)));
typedef unsigned short u16x8v __attribute__((ext_vector_type(8)));

// ---- persistent device scratch (fully overwritten every call) ----
__device__ __attribute__((aligned(16))) unsigned short g_xb2[B_*K_];  // bf16 x [b][k']
__device__ __attribute__((aligned(16))) unsigned short g_xT2[K_*B_];  // bf16 x^T [k'][b]
__device__ __attribute__((aligned(16))) unsigned short g_Wc[C_*1280]; // bf16 cw-scaled W (native layout)
__device__ __attribute__((aligned(16))) unsigned short g_vT[UO_*B_];  // bf16 v^T [uo][b]
__device__ float g_b[C_*U_];                                          // routing logits [c][u]
// barrier state: monotonic generations -> deterministic across graph replays
__device__ unsigned g_gen;             // zero-init at module load
__device__ unsigned g_arrive[NBLK];    // zero-init at module load

union ShMem {
    unsigned short prep_lds[32*256];                 // 16 KB
    float red[4][16][32];                            // 8 KB
    struct { float agg[2][U_]; float cws[2][U_]; } tb;
};

__device__ __forceinline__ unsigned short f2bf(float f) {
    unsigned u = __builtin_bit_cast(unsigned, f);
    unsigned r = (u + 0x7FFFu + ((u >> 16) & 1u)) >> 16;
    return (unsigned short)r;
}

// ---- grid barrier: flag-array arrive + block-0 poll + gen broadcast ----
__device__ __forceinline__ void gbar(unsigned target) {
    __syncthreads();                                   // block's stores complete (vmcnt drain)
    if (threadIdx.x == 0) {
        __threadfence();                               // release: make stores agent-visible
        __hip_atomic_store(&g_arrive[blockIdx.x], target,
                           __ATOMIC_RELAXED, __HIP_MEMORY_SCOPE_AGENT);
    }
    if (blockIdx.x == 0) {
        int i0 = threadIdx.x, i1 = threadIdx.x + NTHR;
        long spins = 0;
        for (;;) {
            unsigned a = __hip_atomic_load(&g_arrive[i0], __ATOMIC_RELAXED, __HIP_MEMORY_SCOPE_AGENT);
            unsigned b = __hip_atomic_load(&g_arrive[i1], __ATOMIC_RELAXED, __HIP_MEMORY_SCOPE_AGENT);
            int ok = ((int)(a - target) >= 0) & ((int)(b - target) >= 0);
            if (__syncthreads_count(ok) == NTHR) break;
            __builtin_amdgcn_s_sleep(2);
            if (++spins > (1L << 16)) break;           // failsafe: fail fast, never hang
        }
        if (threadIdx.x == 0)
            __hip_atomic_store(&g_gen, target, __ATOMIC_RELAXED, __HIP_MEMORY_SCOPE_AGENT);
    }
    if (threadIdx.x == 0) {
        long spins = 0;
        while ((int)(__hip_atomic_load(&g_gen, __ATOMIC_RELAXED, __HIP_MEMORY_SCOPE_AGENT) - target) < 0) {
            __builtin_amdgcn_s_sleep(8);
            if (++spins > (1L << 18)) break;           // failsafe
        }
        __threadfence();                               // acquire: invalidate stale caches once
    }
    __syncthreads();
}

// ---- phase: prep. 756 tasks: 576 x-tiles (xb2 + xT2) and 180 W-convert (Wc=0.1*W) ----
__device__ void ph_prep(const float* __restrict__ x, const float* __restrict__ W,
                        int bid, int tid, ShMem& sh) {
    int li = tid >> 5, lc = tid & 31;
    for (int task = bid; task < 756; task += NBLK) {
        if (task < 576) {
            int b0 = (task & 15) * 32;
            int c0 = (task >> 4) * 32;
            for (int rep = 0; rep < 32; rep++) {
                float v = x[(b0+rep)*K_ + li*1152 + c0 + lc];
                sh.prep_lds[rep*256 + ((lc*8+li) ^ ((rep&31)<<3))] = f2bf(v);
            }
            __syncthreads();
            {   // xb2: 32 contiguous elems per thread
                int b = tid >> 3, part = tid & 7;
                int swz = (b&31) << 3;
                const u16x8v* lv = (const u16x8v*)sh.prep_lds;
                u16x8v* ov = (u16x8v*)(g_xb2 + (b0+b)*K_ + c0*8 + part*32);
                #pragma unroll
                for (int g = 0; g < 4; g++)
                    ov[g] = lv[(b*256 + ((part*32 + g*8) ^ swz)) >> 3];
            }
            for (int p = 0; p < 8; p++) {   // xT2: 8 threads per k'-row
                int r = p*32 + (tid>>3);
                int bp = (tid&7)*4;
                ushort4 o;
                unsigned short* po = (unsigned short*)&o;
                #pragma unroll
                for (int q = 0; q < 4; q++) {
                    int b = bp + q;
                    po[q] = sh.prep_lds[b*256 + (r ^ ((b&31)<<3))];
                }
                *(ushort4*)(g_xT2 + (c0*8 + r)*B_ + b0 + bp) = o;
            }
            __syncthreads();                // protect lds before next task
        } else {
            int base = (task - 576) * 8192;
            for (int j = 0; j < 8; j++) {
                float4 v = *(const float4*)(W + base + j*1024 + tid*4);
                ushort4 o;
                o.x = f2bf(0.1f*v.x); o.y = f2bf(0.1f*v.y);
                o.z = f2bf(0.1f*v.z); o.w = f2bf(0.1f*v.w);
                *(ushort4*)(g_Wc + base + j*1024 + tid*4) = o;
            }
        }
    }
}

// ---- phase: S = x @ Wc^T fused with squash -> vT (+ final out). 160 tasks. ----
__device__ void ph_s(float* __restrict__ out, int write_out, int bid, int tid, ShMem& sh) {
    if (bid < 160) {
        int lane = tid & 63, w = tid >> 6;
        int mt = bid & 31, nt = bid >> 5;
        int m0 = mt*16, n0 = nt*32;
        int ra = lane & 15, kq = (lane>>4)*8;
        const unsigned short* pa  = g_xb2 + (m0+ra)*K_ + w*2304 + kq;
        const unsigned short* pb0 = g_Wc + (w*288 + (kq>>3))*1280 + (n0+ra)*8;
        const unsigned short* pb1 = pb0 + 128;
        f32x4 acc0 = {0.f,0.f,0.f,0.f};
        f32x4 acc1 = {0.f,0.f,0.f,0.f};
        #pragma unroll 6
        for (int s = 0; s < 72; s++) {          // K/wave = 2304
            bf16x8 a  = *(const bf16x8*)pa;
            bf16x8 b0 = *(const bf16x8*)pb0;
            bf16x8 b1 = *(const bf16x8*)pb1;
            acc0 = __builtin_amdgcn_mfma_f32_16x16x32_bf16(a, b0, acc0, 0, 0, 0);
            acc1 = __builtin_amdgcn_mfma_f32_16x16x32_bf16(a, b1, acc1, 0, 0, 0);
            pa += 32; pb0 += 5120; pb1 += 5120; // +4 channels
        }
        int row = (lane>>4)*4, col = lane & 15;
        #pragma unroll
        for (int r = 0; r < 4; r++) {
            sh.red[w][row+r][col]    = acc0[r];
            sh.red[w][row+r][col+16] = acc1[r];
        }
        __syncthreads();
        int g = tid >> 3, brow = g & 15, uh = g >> 4, o = (tid & 7)*2;
        int cA = uh*16 + o, cB = cA + 1;
        float t0 = sh.red[0][brow][cA] + sh.red[1][brow][cA] + sh.red[2][brow][cA] + sh.red[3][brow][cA];
        float t1 = sh.red[0][brow][cB] + sh.red[1][brow][cB] + sh.red[2][brow][cB] + sh.red[3][brow][cB];
        float nrm = t0*t0 + t1*t1;
        nrm += __shfl_xor(nrm, 1);
        nrm += __shfl_xor(nrm, 2);
        nrm += __shfl_xor(nrm, 4);
        float f = nrm / ((1.f + nrm) * sqrtf(nrm));
        float v0 = t0*f, v1 = t1*f;
        int ug = nt*2 + uh, bg = m0 + brow;
        g_vT[(ug*16+o)*B_ + bg]   = f2bf(v0);
        g_vT[(ug*16+o+1)*B_ + bg] = f2bf(v1);
        if (write_out) {
            float2 o2; o2.x = v0; o2.y = v1;
            *(float2*)(out + (bg*10 + ug)*16 + o) = o2;
        }
        __syncthreads();                        // sh.red safe before next phase
    }
}

// ---- phase: TB. T' in regs + agree + b-update + softmax + next Wc. 576 tasks. ----
__device__ void ph_tb(const float* __restrict__ W, int first, int bid, int tid, ShMem& sh) {
    int lane = tid & 63, w = tid >> 6;
    for (int task = bid; task < 576; task += NBLK) {
        int c0 = task * 2;
        int ra = lane & 15, kq = (lane>>4)*8;
        int ct = lane >> 5;
        int i0 = ((lane>>4) & 1) * 4;
        int o  = lane & 15;
        const unsigned short* pa0 = g_xT2 + (c0*8 + ra)*B_ + kq;
        for (int nt = w; nt < 5; nt += 4) {     // wave 0 also covers tile 4
            int n0 = nt*32;
            const unsigned short* pa  = pa0;
            const unsigned short* pb0 = g_vT + (n0+ra)*B_ + kq;
            const unsigned short* pb1 = pb0 + 16*B_;
            f32x4 acc0 = {0.f,0.f,0.f,0.f};
            f32x4 acc1 = {0.f,0.f,0.f,0.f};
            #pragma unroll 4
            for (int s = 0; s < 16; s++) {      // K = 512
                bf16x8 a  = *(const bf16x8*)pa;
                bf16x8 b0 = *(const bf16x8*)pb0;
                bf16x8 b1 = *(const bf16x8*)pb1;
                acc0 = __builtin_amdgcn_mfma_f32_16x16x32_bf16(a, b0, acc0, 0, 0, 0);
                acc1 = __builtin_amdgcn_mfma_f32_16x16x32_bf16(a, b1, acc1, 0, 0, 0);
                pa += 32; pb0 += 32; pb1 += 32;
            }
            const float* wr = W + (c0+ct)*1280;
            float4 wa = *(const float4*)(wr + (2*nt  )*128 + o*8 + i0);
            float4 wb = *(const float4*)(wr + (2*nt+1)*128 + o*8 + i0);
            float p0 = wa.x*acc0[0] + wa.y*acc0[1] + wa.z*acc0[2] + wa.w*acc0[3];
            float p1 = wb.x*acc1[0] + wb.y*acc1[1] + wb.z*acc1[2] + wb.w*acc1[3];
            #pragma unroll
            for (int m = 1; m < 32; m <<= 1) {
                p0 += __shfl_xor(p0, m);
                p1 += __shfl_xor(p1, m);
            }
            if ((lane & 31) == 0) {
                sh.tb.agg[ct][2*nt]   = p0 * (1.f/512.f);
                sh.tb.agg[ct][2*nt+1] = p1 * (1.f/512.f);
            }
        }
        __syncthreads();
        if (tid < 2) {                          // per-channel b-update + softmax
            int c = c0 + tid;
            float bv[U_];
            float mx = -3e38f;
            #pragma unroll
            for (int u = 0; u < U_; u++) {
                float v = sh.tb.agg[tid][u];
                if (!first) v += g_b[c*U_ + u];
                g_b[c*U_ + u] = v;
                bv[u] = v;
                mx = fmaxf(mx, v);
            }
            float sm = 0.f;
            #pragma unroll
            for (int u = 0; u < U_; u++) { bv[u] = expf(bv[u] - mx); sm += bv[u]; }
            float inv = 1.f/sm;
            #pragma unroll
            for (int u = 0; u < U_; u++) sh.tb.cws[tid][u] = bv[u]*inv;
        }
        __syncthreads();
        for (int e = tid*8; e < 2560; e += NTHR*8) {   // next-iter Wc for both channels
            int ch  = (e >= 1280) ? 1 : 0;
            int off = e - ch*1280;
            int u   = off >> 7;
            float s = sh.tb.cws[ch][u];
            const float* wp = W + (c0+ch)*1280 + off;
            float4 a4 = *(const float4*)wp;
            float4 b4 = *(const float4*)(wp + 4);
            u16x8v ov;
            ov[0] = f2bf(a4.x*s); ov[1] = f2bf(a4.y*s); ov[2] = f2bf(a4.z*s); ov[3] = f2bf(a4.w*s);
            ov[4] = f2bf(b4.x*s); ov[5] = f2bf(b4.y*s); ov[6] = f2bf(b4.z*s); ov[7] = f2bf(b4.w*s);
            *(u16x8v*)(g_Wc + (c0+ch)*1280 + off) = ov;
        }
        __syncthreads();                        // sh.tb safe before next task/phase
    }
}

// ---- the single persistent kernel ----
__global__ __launch_bounds__(NTHR, 2) void k_all(const float* __restrict__ x,
                                                 const float* __restrict__ W,
                                                 float* __restrict__ out) {
    __shared__ ShMem sh;
    int bid = blockIdx.x, tid = threadIdx.x;
    // barrier generation base (stable between stream-serialized calls; monotonic)
    unsigned G0 = __hip_atomic_load(&g_gen, __ATOMIC_RELAXED, __HIP_MEMORY_SCOPE_AGENT);
    ph_prep(x, W, bid, tid, sh);
    gbar(G0 + 1);
    ph_s(out, 0, bid, tid, sh);     // t=0 (Wc = 0.1*W)
    gbar(G0 + 2);
    ph_tb(W, 1, bid, tid, sh);
    gbar(G0 + 3);
    ph_s(out, 0, bid, tid, sh);     // t=1
    gbar(G0 + 4);
    ph_tb(W, 0, bid, tid, sh);
    gbar(G0 + 5);
    ph_s(out, 1, bid, tid, sh);     // t=2, writes final output
}

extern "C" void kernel_launch(void* const* d_in, const int* in_sizes, int n_in,
                              void* d_out, int out_size, void* d_ws, size_t ws_size,
                              hipStream_t stream) {
    const float* x = (const float*)d_in[0];
    const float* W = (const float*)d_in[1];
    float* out = (float*)d_out;
    k_all<<<dim3(NBLK), dim3(NTHR), 0, stream>>>(x, W, out);
}

// Round 10
// 177.068 us; speedup vs baseline: 5.9824x; 1.3998x over previous
//
#include <hip/hip_runtime.h>
#include <math.h>

// k' = c*8 + i (c-major): B-matrix [uo][k'] is W's native [c][u][o][i] layout.
// Two dispatches: k_prep (static bf16 layouts; dispatch boundary = visibility)
// then k_mega (S0,TB0,S1,TB1,S2 with 4 fence-free flag barriers; all dynamic
// cross-block data via system-scope relaxed atomics = write-through coherent).
#define B_ 512
#define C_ 1152
#define U_ 10
#define O_ 16
#define I_ 8
#define K_ 9216
#define UO_ 160
#define NBLK 512
#define NTHR 256

typedef short bf16x8 __attribute__((ext_vector_type(8)));
typedef float f32x4 __attribute__((ext_vector_type(4)));
typedef unsigned short u16x8v __attribute__((ext_vector_type(8)));
typedef unsigned long long u64t;

// ---- persistent device scratch (fully overwritten every call) ----
__device__ __attribute__((aligned(16))) unsigned short g_xb2[B_*K_];  // bf16 x [b][k']   (static per call)
__device__ __attribute__((aligned(16))) unsigned short g_xT2[K_*B_];  // bf16 x^T [k'][b] (static per call)
__device__ __attribute__((aligned(16))) unsigned short g_Wc[C_*1280]; // bf16 cw-scaled W (DYNAMIC: system-scope)
__device__ __attribute__((aligned(16))) unsigned g_vT32[UO_*B_/2];    // bf16 v^T [uo][b] packed u32 (DYNAMIC)
__device__ float g_b[C_*U_];                                          // logits (block-local across phases)
__device__ unsigned g_gen;             // barrier generation (monotonic across replays)
__device__ unsigned g_arrive[NBLK];    // per-block arrival flags

__device__ __forceinline__ unsigned short f2bf(float f) {
    unsigned u = __builtin_bit_cast(unsigned, f);
    unsigned r = (u + 0x7FFFu + ((u >> 16) & 1u)) >> 16;
    return (unsigned short)r;
}

// system-scope coherent access helpers: bypass L1/L2, no fences needed
__device__ __forceinline__ bf16x8 ld_sys16(const unsigned short* p) {
    union { u64t q[2]; bf16x8 v; } u;
    u.q[0] = __hip_atomic_load((const u64t*)p,     __ATOMIC_RELAXED, __HIP_MEMORY_SCOPE_SYSTEM);
    u.q[1] = __hip_atomic_load(((const u64t*)p)+1, __ATOMIC_RELAXED, __HIP_MEMORY_SCOPE_SYSTEM);
    return u.v;
}
__device__ __forceinline__ void st_sys16(unsigned short* p, u16x8v v) {
    union { u16x8v v; u64t q[2]; } u; u.v = v;
    __hip_atomic_store((u64t*)p,     u.q[0], __ATOMIC_RELAXED, __HIP_MEMORY_SCOPE_SYSTEM);
    __hip_atomic_store(((u64t*)p)+1, u.q[1], __ATOMIC_RELAXED, __HIP_MEMORY_SCOPE_SYSTEM);
}

// ---- dispatch 1: prep. x -> bf16 [b][k'] + [k'][b]; Wc = bf16(0.1*W) ----
__global__ __launch_bounds__(256) void k_prep(const float* __restrict__ x,
                                              const float* __restrict__ W) {
    __shared__ unsigned short lds[32*256];
    int task = blockIdx.x, tid = threadIdx.x;
    if (task < 576) {
        int b0 = (task & 15) * 32;
        int c0 = (task >> 4) * 32;
        int li = tid >> 5, lc = tid & 31;
        for (int rep = 0; rep < 32; rep++) {
            float v = x[(b0+rep)*K_ + li*1152 + c0 + lc];
            lds[rep*256 + ((lc*8+li) ^ ((rep&31)<<3))] = f2bf(v);
        }
        __syncthreads();
        {   // xb2: 32 contiguous elems per thread
            int b = tid >> 3, part = tid & 7;
            int swz = (b&31) << 3;
            const u16x8v* lv = (const u16x8v*)lds;
            u16x8v* ov = (u16x8v*)(g_xb2 + (b0+b)*K_ + c0*8 + part*32);
            #pragma unroll
            for (int g = 0; g < 4; g++)
                ov[g] = lv[(b*256 + ((part*32 + g*8) ^ swz)) >> 3];
        }
        for (int p = 0; p < 8; p++) {   // xT2: 8 threads per k'-row
            int r = p*32 + (tid>>3);
            int bp = (tid&7)*4;
            ushort4 o;
            unsigned short* po = (unsigned short*)&o;
            #pragma unroll
            for (int q = 0; q < 4; q++) {
                int b = bp + q;
                po[q] = lds[b*256 + (r ^ ((b&31)<<3))];
            }
            *(ushort4*)(g_xT2 + (c0*8 + r)*B_ + b0 + bp) = o;
        }
    } else {
        int base = (task - 576) * 8192;
        for (int j = 0; j < 8; j++) {
            float4 v = *(const float4*)(W + base + j*1024 + tid*4);
            ushort4 o;
            o.x = f2bf(0.1f*v.x); o.y = f2bf(0.1f*v.y);
            o.z = f2bf(0.1f*v.z); o.w = f2bf(0.1f*v.w);
            *(ushort4*)(g_Wc + base + j*1024 + tid*4) = o;
        }
    }
}

union ShMem {
    float red[4][16][32];                            // 8 KB
    struct { float agg[2][U_]; float cws[2][U_]; } tb;
};

// ---- grid barrier: flag arrive + block-0 sweep + gen broadcast; NO fences ----
__device__ __forceinline__ void gbar(unsigned target) {
    __syncthreads();                    // drains vmcnt: payload stores at coherence point
    if (threadIdx.x == 0)
        __hip_atomic_store(&g_arrive[blockIdx.x], target,
                           __ATOMIC_RELAXED, __HIP_MEMORY_SCOPE_SYSTEM);
    if (blockIdx.x == 0) {
        int i0 = threadIdx.x, i1 = threadIdx.x + NTHR;
        long spins = 0;
        for (;;) {
            unsigned a = __hip_atomic_load(&g_arrive[i0], __ATOMIC_RELAXED, __HIP_MEMORY_SCOPE_SYSTEM);
            unsigned b = __hip_atomic_load(&g_arrive[i1], __ATOMIC_RELAXED, __HIP_MEMORY_SCOPE_SYSTEM);
            int ok = ((int)(a - target) >= 0) & ((int)(b - target) >= 0);
            if (__syncthreads_count(ok) == NTHR) break;
            __builtin_amdgcn_s_sleep(4);
            if (++spins > (1L << 17)) break;        // failsafe: fail fast, never hang
        }
        if (threadIdx.x == 0)
            __hip_atomic_store(&g_gen, target, __ATOMIC_RELAXED, __HIP_MEMORY_SCOPE_SYSTEM);
    }
    if (threadIdx.x == 0) {
        long spins = 0;
        while ((int)(__hip_atomic_load(&g_gen, __ATOMIC_RELAXED, __HIP_MEMORY_SCOPE_SYSTEM) - target) < 0) {
            __builtin_amdgcn_s_sleep(8);
            if (++spins > (1L << 18)) break;        // failsafe
        }
    }
    __syncthreads();
}

// ---- phase: S = x @ Wc^T fused with squash -> vT (+ final out). 160 tasks. ----
__device__ void ph_s(float* __restrict__ out, int write_out, int bid, int tid, ShMem& sh) {
    if (bid < 160) {
        int lane = tid & 63, w = tid >> 6;
        int mt = bid & 31, nt = bid >> 5;
        int m0 = mt*16, n0 = nt*32;
        int ra = lane & 15, kq = (lane>>4)*8;
        const unsigned short* pa  = g_xb2 + (m0+ra)*K_ + w*2304 + kq;
        const unsigned short* pb0 = g_Wc + (w*288 + (kq>>3))*1280 + (n0+ra)*8;
        const unsigned short* pb1 = pb0 + 128;
        f32x4 acc0 = {0.f,0.f,0.f,0.f};
        f32x4 acc1 = {0.f,0.f,0.f,0.f};
        #pragma unroll 6
        for (int s = 0; s < 72; s++) {          // K/wave = 2304
            bf16x8 a  = *(const bf16x8*)pa;
            bf16x8 b0 = ld_sys16(pb0);
            bf16x8 b1 = ld_sys16(pb1);
            acc0 = __builtin_amdgcn_mfma_f32_16x16x32_bf16(a, b0, acc0, 0, 0, 0);
            acc1 = __builtin_amdgcn_mfma_f32_16x16x32_bf16(a, b1, acc1, 0, 0, 0);
            pa += 32; pb0 += 5120; pb1 += 5120; // +4 channels
        }
        int row = (lane>>4)*4, col = lane & 15;
        #pragma unroll
        for (int r = 0; r < 4; r++) {
            sh.red[w][row+r][col]    = acc0[r];
            sh.red[w][row+r][col+16] = acc1[r];
        }
        __syncthreads();
        // squash: thread -> (b-pair bp, u, o); u32-packed coherent vT store
        int bp = tid >> 5;              // 0..7
        int u  = (tid >> 4) & 1;
        int o  = tid & 15;
        int col2 = u*16 + o;
        float t0 = sh.red[0][2*bp][col2] + sh.red[1][2*bp][col2] + sh.red[2][2*bp][col2] + sh.red[3][2*bp][col2];
        float t1 = sh.red[0][2*bp+1][col2] + sh.red[1][2*bp+1][col2] + sh.red[2][2*bp+1][col2] + sh.red[3][2*bp+1][col2];
        float n0s = t0*t0, n1s = t1*t1;
        #pragma unroll
        for (int m = 1; m < 16; m <<= 1) {
            n0s += __shfl_xor(n0s, m);
            n1s += __shfl_xor(n1s, m);
        }
        float f0 = n0s / ((1.f + n0s) * sqrtf(n0s));
        float f1 = n1s / ((1.f + n1s) * sqrtf(n1s));
        float v0 = t0*f0, v1 = t1*f1;
        int ug = nt*2 + u;
        int bg = m0 + 2*bp;
        unsigned pack = (unsigned)f2bf(v0) | ((unsigned)f2bf(v1) << 16);
        __hip_atomic_store(&g_vT32[((ug*16+o)*B_ + bg) >> 1], pack,
                           __ATOMIC_RELAXED, __HIP_MEMORY_SCOPE_SYSTEM);
        if (write_out) {
            out[(bg*10 + ug)*16 + o]       = v0;
            out[((bg+1)*10 + ug)*16 + o]   = v1;
        }
        __syncthreads();                        // sh.red safe before next phase
    }
}

// ---- phase: TB. T' in regs + agree + b-update + softmax + next Wc. 576 tasks. ----
__device__ void ph_tb(const float* __restrict__ W, int first, int bid, int tid, ShMem& sh) {
    int lane = tid & 63, w = tid >> 6;
    const unsigned short* vT = (const unsigned short*)g_vT32;
    for (int task = bid; task < 576; task += NBLK) {
        int c0 = task * 2;
        int ra = lane & 15, kq = (lane>>4)*8;
        int ct = lane >> 5;
        int i0 = ((lane>>4) & 1) * 4;
        int o  = lane & 15;
        const unsigned short* pa0 = g_xT2 + (c0*8 + ra)*B_ + kq;
        for (int nt = w; nt < 5; nt += 4) {     // wave 0 also covers tile 4
            int n0 = nt*32;
            const unsigned short* pa  = pa0;
            const unsigned short* pb0 = vT + (n0+ra)*B_ + kq;
            const unsigned short* pb1 = pb0 + 16*B_;
            f32x4 acc0 = {0.f,0.f,0.f,0.f};
            f32x4 acc1 = {0.f,0.f,0.f,0.f};
            #pragma unroll 4
            for (int s = 0; s < 16; s++) {      // K = 512
                bf16x8 a  = *(const bf16x8*)pa;
                bf16x8 b0 = ld_sys16(pb0);
                bf16x8 b1 = ld_sys16(pb1);
                acc0 = __builtin_amdgcn_mfma_f32_16x16x32_bf16(a, b0, acc0, 0, 0, 0);
                acc1 = __builtin_amdgcn_mfma_f32_16x16x32_bf16(a, b1, acc1, 0, 0, 0);
                pa += 32; pb0 += 32; pb1 += 32;
            }
            const float* wr = W + (c0+ct)*1280;
            float4 wa = *(const float4*)(wr + (2*nt  )*128 + o*8 + i0);
            float4 wb = *(const float4*)(wr + (2*nt+1)*128 + o*8 + i0);
            float p0 = wa.x*acc0[0] + wa.y*acc0[1] + wa.z*acc0[2] + wa.w*acc0[3];
            float p1 = wb.x*acc1[0] + wb.y*acc1[1] + wb.z*acc1[2] + wb.w*acc1[3];
            #pragma unroll
            for (int m = 1; m < 32; m <<= 1) {
                p0 += __shfl_xor(p0, m);
                p1 += __shfl_xor(p1, m);
            }
            if ((lane & 31) == 0) {
                sh.tb.agg[ct][2*nt]   = p0 * (1.f/512.f);
                sh.tb.agg[ct][2*nt+1] = p1 * (1.f/512.f);
            }
        }
        __syncthreads();
        if (tid < 2) {                          // per-channel b-update + softmax (block-local g_b)
            int c = c0 + tid;
            float bv[U_];
            float mx = -3e38f;
            #pragma unroll
            for (int u = 0; u < U_; u++) {
                float v = sh.tb.agg[tid][u];
                if (!first) v += g_b[c*U_ + u];
                g_b[c*U_ + u] = v;
                bv[u] = v;
                mx = fmaxf(mx, v);
            }
            float sm = 0.f;
            #pragma unroll
            for (int u = 0; u < U_; u++) { bv[u] = expf(bv[u] - mx); sm += bv[u]; }
            float inv = 1.f/sm;
            #pragma unroll
            for (int u = 0; u < U_; u++) sh.tb.cws[tid][u] = bv[u]*inv;
        }
        __syncthreads();
        for (int e = tid*8; e < 2560; e += NTHR*8) {   // next-iter Wc, coherent stores
            int ch  = (e >= 1280) ? 1 : 0;
            int off = e - ch*1280;
            int u   = off >> 7;
            float s = sh.tb.cws[ch][u];
            const float* wp = W + (c0+ch)*1280 + off;
            float4 a4 = *(const float4*)wp;
            float4 b4 = *(const float4*)(wp + 4);
            u16x8v ov;
            ov[0] = f2bf(a4.x*s); ov[1] = f2bf(a4.y*s); ov[2] = f2bf(a4.z*s); ov[3] = f2bf(a4.w*s);
            ov[4] = f2bf(b4.x*s); ov[5] = f2bf(b4.y*s); ov[6] = f2bf(b4.z*s); ov[7] = f2bf(b4.w*s);
            st_sys16(g_Wc + (c0+ch)*1280 + off, ov);
        }
        __syncthreads();                        // sh.tb safe before next task/phase
    }
}

// ---- dispatch 2: persistent kernel over S0..S2 with 4 flag barriers ----
__global__ __launch_bounds__(NTHR, 2) void k_mega(const float* __restrict__ W,
                                                  float* __restrict__ out) {
    __shared__ ShMem sh;
    __shared__ unsigned sG0;
    int bid = blockIdx.x, tid = threadIdx.x;
    if (tid == 0)
        sG0 = __hip_atomic_load(&g_gen, __ATOMIC_RELAXED, __HIP_MEMORY_SCOPE_SYSTEM);
    __syncthreads();
    unsigned G0 = sG0;
    ph_s(out, 0, bid, tid, sh);     // t=0 (Wc = 0.1*W from prep)
    gbar(G0 + 1);
    ph_tb(W, 1, bid, tid, sh);
    gbar(G0 + 2);
    ph_s(out, 0, bid, tid, sh);     // t=1
    gbar(G0 + 3);
    ph_tb(W, 0, bid, tid, sh);
    gbar(G0 + 4);
    ph_s(out, 1, bid, tid, sh);     // t=2, writes final output
}

extern "C" void kernel_launch(void* const* d_in, const int* in_sizes, int n_in,
                              void* d_out, int out_size, void* d_ws, size_t ws_size,
                              hipStream_t stream) {
    const float* x = (const float*)d_in[0];
    const float* W = (const float*)d_in[1];
    float* out = (float*)d_out;
    k_prep<<<dim3(756), dim3(256), 0, stream>>>(x, W);
    k_mega<<<dim3(NBLK), dim3(NTHR), 0, stream>>>(W, out);
}

// Round 11
// 145.324 us; speedup vs baseline: 7.2892x; 1.2184x over previous
//
#include <hip/hip_runtime.h>
#include <math.h>

// k' = c*8 + i (c-major): B-matrix [uo][k'] is W's native [c][u][o][i] layout.
// Two dispatches: k_prep (static bf16 layouts), then k_mega (S0,TB0,S1,TB1,S2
// with 4 flag barriers).  Cross-block dynamic data is VERSIONED (Wc x3, vT x2):
// producers store write-through (system scope, no-allocate), consumers use plain
// CACHED loads on addresses virgin to their XCD this kernel instance.
#define B_ 512
#define C_ 1152
#define U_ 10
#define O_ 16
#define I_ 8
#define K_ 9216
#define UO_ 160
#define NBLK 256
#define NTHR 256

typedef short bf16x8 __attribute__((ext_vector_type(8)));
typedef float f32x4 __attribute__((ext_vector_type(4)));
typedef unsigned short u16x8v __attribute__((ext_vector_type(8)));
typedef unsigned long long u64t;

// ---- persistent device scratch (fully overwritten every call) ----
__device__ __attribute__((aligned(16))) unsigned short g_xb2[B_*K_];     // bf16 x [b][k']
__device__ __attribute__((aligned(16))) unsigned short g_xT2[K_*B_];     // bf16 x^T [k'][b]
__device__ __attribute__((aligned(16))) unsigned short g_Wc[3][C_*1280]; // bf16 cw-scaled W, 3 versions
__device__ __attribute__((aligned(16))) unsigned g_vT32[2][UO_*B_/2];    // bf16 v^T packed u32, 2 versions
__device__ float g_b[C_*U_];           // logits (same block reads/writes its own c's)
__device__ unsigned g_gen;             // barrier generation (monotonic across replays)
__device__ unsigned g_arrive[NBLK];    // per-block arrival flags

__device__ __forceinline__ unsigned short f2bf(float f) {
    unsigned u = __builtin_bit_cast(unsigned, f);
    unsigned r = (u + 0x7FFFu + ((u >> 16) & 1u)) >> 16;
    return (unsigned short)r;
}

// write-through store (system scope = sc0 sc1, no L1/L2 allocate)
__device__ __forceinline__ void st_sys16(unsigned short* p, u16x8v v) {
    union { u16x8v v; u64t q[2]; } u; u.v = v;
    __hip_atomic_store((u64t*)p,     u.q[0], __ATOMIC_RELAXED, __HIP_MEMORY_SCOPE_SYSTEM);
    __hip_atomic_store(((u64t*)p)+1, u.q[1], __ATOMIC_RELAXED, __HIP_MEMORY_SCOPE_SYSTEM);
}

// ---- dispatch 1: prep. x -> bf16 [b][k'] + [k'][b]; Wc[0] = bf16(0.1*W) ----
__global__ __launch_bounds__(256) void k_prep(const float* __restrict__ x,
                                              const float* __restrict__ W) {
    __shared__ unsigned short lds[32*256];
    int task = blockIdx.x, tid = threadIdx.x;
    if (task < 576) {
        int b0 = (task & 15) * 32;
        int c0 = (task >> 4) * 32;
        int li = tid >> 5, lc = tid & 31;
        for (int rep = 0; rep < 32; rep++) {
            float v = x[(b0+rep)*K_ + li*1152 + c0 + lc];
            lds[rep*256 + ((lc*8+li) ^ ((rep&31)<<3))] = f2bf(v);
        }
        __syncthreads();
        {   // xb2: 32 contiguous elems per thread
            int b = tid >> 3, part = tid & 7;
            int swz = (b&31) << 3;
            const u16x8v* lv = (const u16x8v*)lds;
            u16x8v* ov = (u16x8v*)(g_xb2 + (b0+b)*K_ + c0*8 + part*32);
            #pragma unroll
            for (int g = 0; g < 4; g++)
                ov[g] = lv[(b*256 + ((part*32 + g*8) ^ swz)) >> 3];
        }
        for (int p = 0; p < 8; p++) {   // xT2: 8 threads per k'-row
            int r = p*32 + (tid>>3);
            int bp = (tid&7)*4;
            ushort4 o;
            unsigned short* po = (unsigned short*)&o;
            #pragma unroll
            for (int q = 0; q < 4; q++) {
                int b = bp + q;
                po[q] = lds[b*256 + (r ^ ((b&31)<<3))];
            }
            *(ushort4*)(g_xT2 + (c0*8 + r)*B_ + b0 + bp) = o;
        }
    } else {
        int base = (task - 576) * 8192;
        for (int j = 0; j < 8; j++) {
            float4 v = *(const float4*)(W + base + j*1024 + tid*4);
            ushort4 o;
            o.x = f2bf(0.1f*v.x); o.y = f2bf(0.1f*v.y);
            o.z = f2bf(0.1f*v.z); o.w = f2bf(0.1f*v.w);
            *(ushort4*)(&g_Wc[0][0] + base + j*1024 + tid*4) = o;
        }
    }
}

union ShMem {
    float red[4][16][32];                            // 8 KB
    struct { float agg[2][U_]; float cws[2][U_]; } tb;
};

// ---- grid barrier: flag arrive + block-0 sweep + gen broadcast; no fences ----
__device__ __forceinline__ void gbar(unsigned target) {
    __syncthreads();                    // drains vmcnt: payload stores at coherence point
    if (threadIdx.x == 0)
        __hip_atomic_store(&g_arrive[blockIdx.x], target,
                           __ATOMIC_RELAXED, __HIP_MEMORY_SCOPE_SYSTEM);
    if (blockIdx.x == 0) {
        long spins = 0;
        for (;;) {
            unsigned a = __hip_atomic_load(&g_arrive[threadIdx.x],
                                           __ATOMIC_RELAXED, __HIP_MEMORY_SCOPE_SYSTEM);
            if (__syncthreads_count((int)(a - target) >= 0) == NTHR) break;
            __builtin_amdgcn_s_sleep(4);
            if (++spins > (1L << 17)) break;        // failsafe: fail fast, never hang
        }
        if (threadIdx.x == 0)
            __hip_atomic_store(&g_gen, target, __ATOMIC_RELAXED, __HIP_MEMORY_SCOPE_SYSTEM);
    }
    if (threadIdx.x == 0) {
        long spins = 0;
        while ((int)(__hip_atomic_load(&g_gen, __ATOMIC_RELAXED, __HIP_MEMORY_SCOPE_SYSTEM) - target) < 0) {
            __builtin_amdgcn_s_sleep(8);
            if (++spins > (1L << 18)) break;        // failsafe
        }
    }
    __syncthreads();
}

// ---- phase: S = x @ Wc^T fused with squash -> vT (+ final out). 160 tasks. ----
// Wcr: CACHED read (virgin addresses).  vtw: sys-scope packed store (or null on t=2).
__device__ void ph_s(const unsigned short* __restrict__ Wcr, unsigned* vtw,
                     float* __restrict__ out, int bid, int tid, ShMem& sh) {
    if (bid < 160) {
        int lane = tid & 63, w = tid >> 6;
        int mt = bid & 31, nt = bid >> 5;
        int m0 = mt*16, n0 = nt*32;
        int ra = lane & 15, kq = (lane>>4)*8;
        const unsigned short* pa  = g_xb2 + (m0+ra)*K_ + w*2304 + kq;
        const unsigned short* pb0 = Wcr + (w*288 + (kq>>3))*1280 + (n0+ra)*8;
        const unsigned short* pb1 = pb0 + 128;
        f32x4 acc0 = {0.f,0.f,0.f,0.f};
        f32x4 acc1 = {0.f,0.f,0.f,0.f};
        #pragma unroll 6
        for (int s = 0; s < 72; s++) {          // K/wave = 2304
            bf16x8 a  = *(const bf16x8*)pa;
            bf16x8 b0 = *(const bf16x8*)pb0;
            bf16x8 b1 = *(const bf16x8*)pb1;
            acc0 = __builtin_amdgcn_mfma_f32_16x16x32_bf16(a, b0, acc0, 0, 0, 0);
            acc1 = __builtin_amdgcn_mfma_f32_16x16x32_bf16(a, b1, acc1, 0, 0, 0);
            pa += 32; pb0 += 5120; pb1 += 5120; // +4 channels
        }
        int row = (lane>>4)*4, col = lane & 15;
        #pragma unroll
        for (int r = 0; r < 4; r++) {
            sh.red[w][row+r][col]    = acc0[r];
            sh.red[w][row+r][col+16] = acc1[r];
        }
        __syncthreads();
        // squash: thread -> (b-pair bp, u, o)
        int bp = tid >> 5;              // 0..7
        int u  = (tid >> 4) & 1;
        int o  = tid & 15;
        int col2 = u*16 + o;
        float t0 = sh.red[0][2*bp][col2] + sh.red[1][2*bp][col2] + sh.red[2][2*bp][col2] + sh.red[3][2*bp][col2];
        float t1 = sh.red[0][2*bp+1][col2] + sh.red[1][2*bp+1][col2] + sh.red[2][2*bp+1][col2] + sh.red[3][2*bp+1][col2];
        float n0s = t0*t0, n1s = t1*t1;
        #pragma unroll
        for (int m = 1; m < 16; m <<= 1) {
            n0s += __shfl_xor(n0s, m);
            n1s += __shfl_xor(n1s, m);
        }
        float f0 = n0s / ((1.f + n0s) * sqrtf(n0s));
        float f1 = n1s / ((1.f + n1s) * sqrtf(n1s));
        float v0 = t0*f0, v1 = t1*f1;
        int ug = nt*2 + u;
        int bg = m0 + 2*bp;
        if (vtw) {
            unsigned pack = (unsigned)f2bf(v0) | ((unsigned)f2bf(v1) << 16);
            __hip_atomic_store(&vtw[((ug*16+o)*B_ + bg) >> 1], pack,
                               __ATOMIC_RELAXED, __HIP_MEMORY_SCOPE_SYSTEM);
        } else {
            out[(bg*10 + ug)*16 + o]       = v0;
            out[((bg+1)*10 + ug)*16 + o]   = v1;
        }
        __syncthreads();                        // sh.red safe before next phase
    }
}

// ---- phase: TB. T' in regs + agree + b-update + softmax + next Wc. 576 tasks. ----
// vtr: CACHED read (virgin).  Wcw: sys-scope write-through.
__device__ void ph_tb(const float* __restrict__ W, const unsigned* vtr,
                      unsigned short* Wcw, int first, int bid, int tid, ShMem& sh) {
    int lane = tid & 63, w = tid >> 6;
    const unsigned short* vT = (const unsigned short*)vtr;
    for (int task = bid; task < 576; task += NBLK) {
        int c0 = task * 2;
        int ra = lane & 15, kq = (lane>>4)*8;
        int ct = lane >> 5;
        int i0 = ((lane>>4) & 1) * 4;
        int o  = lane & 15;
        const unsigned short* pa0 = g_xT2 + (c0*8 + ra)*B_ + kq;
        for (int nt = w; nt < 5; nt += 4) {     // wave 0 also covers tile 4
            int n0 = nt*32;
            const unsigned short* pa  = pa0;
            const unsigned short* pb0 = vT + (n0+ra)*B_ + kq;
            const unsigned short* pb1 = pb0 + 16*B_;
            f32x4 acc0 = {0.f,0.f,0.f,0.f};
            f32x4 acc1 = {0.f,0.f,0.f,0.f};
            #pragma unroll 4
            for (int s = 0; s < 16; s++) {      // K = 512
                bf16x8 a  = *(const bf16x8*)pa;
                bf16x8 b0 = *(const bf16x8*)pb0;
                bf16x8 b1 = *(const bf16x8*)pb1;
                acc0 = __builtin_amdgcn_mfma_f32_16x16x32_bf16(a, b0, acc0, 0, 0, 0);
                acc1 = __builtin_amdgcn_mfma_f32_16x16x32_bf16(a, b1, acc1, 0, 0, 0);
                pa += 32; pb0 += 32; pb1 += 32;
            }
            const float* wr = W + (c0+ct)*1280;
            float4 wa = *(const float4*)(wr + (2*nt  )*128 + o*8 + i0);
            float4 wb = *(const float4*)(wr + (2*nt+1)*128 + o*8 + i0);
            float p0 = wa.x*acc0[0] + wa.y*acc0[1] + wa.z*acc0[2] + wa.w*acc0[3];
            float p1 = wb.x*acc1[0] + wb.y*acc1[1] + wb.z*acc1[2] + wb.w*acc1[3];
            #pragma unroll
            for (int m = 1; m < 32; m <<= 1) {
                p0 += __shfl_xor(p0, m);
                p1 += __shfl_xor(p1, m);
            }
            if ((lane & 31) == 0) {
                sh.tb.agg[ct][2*nt]   = p0 * (1.f/512.f);
                sh.tb.agg[ct][2*nt+1] = p1 * (1.f/512.f);
            }
        }
        __syncthreads();
        if (tid < 2) {                          // per-channel b-update + softmax
            int c = c0 + tid;
            float bv[U_];
            float mx = -3e38f;
            #pragma unroll
            for (int u = 0; u < U_; u++) {
                float v = sh.tb.agg[tid][u];
                if (!first) v += g_b[c*U_ + u];
                g_b[c*U_ + u] = v;
                bv[u] = v;
                mx = fmaxf(mx, v);
            }
            float sm = 0.f;
            #pragma unroll
            for (int u = 0; u < U_; u++) { bv[u] = expf(bv[u] - mx); sm += bv[u]; }
            float inv = 1.f/sm;
            #pragma unroll
            for (int u = 0; u < U_; u++) sh.tb.cws[tid][u] = bv[u]*inv;
        }
        __syncthreads();
        for (int e = tid*8; e < 2560; e += NTHR*8) {   // next-iter Wc, write-through
            int ch  = (e >= 1280) ? 1 : 0;
            int off = e - ch*1280;
            int u   = off >> 7;
            float s = sh.tb.cws[ch][u];
            const float* wp = W + (c0+ch)*1280 + off;
            float4 a4 = *(const float4*)wp;
            float4 b4 = *(const float4*)(wp + 4);
            u16x8v ov;
            ov[0] = f2bf(a4.x*s); ov[1] = f2bf(a4.y*s); ov[2] = f2bf(a4.z*s); ov[3] = f2bf(a4.w*s);
            ov[4] = f2bf(b4.x*s); ov[5] = f2bf(b4.y*s); ov[6] = f2bf(b4.z*s); ov[7] = f2bf(b4.w*s);
            st_sys16(Wcw + (c0+ch)*1280 + off, ov);
        }
        __syncthreads();                        // sh.tb safe before next task/phase
    }
}

// ---- dispatch 2: persistent kernel, 5 phases, 4 flag barriers ----
__global__ __launch_bounds__(NTHR) void k_mega(const float* __restrict__ W,
                                               float* __restrict__ out) {
    __shared__ ShMem sh;
    __shared__ unsigned sG0;
    int bid = blockIdx.x, tid = threadIdx.x;
    if (tid == 0)
        sG0 = __hip_atomic_load(&g_gen, __ATOMIC_RELAXED, __HIP_MEMORY_SCOPE_SYSTEM);
    __syncthreads();
    unsigned G0 = sG0;
    ph_s(&g_Wc[0][0], &g_vT32[0][0], out, bid, tid, sh);    // t=0
    gbar(G0 + 1);
    ph_tb(W, &g_vT32[0][0], &g_Wc[1][0], 1, bid, tid, sh);
    gbar(G0 + 2);
    ph_s(&g_Wc[1][0], &g_vT32[1][0], out, bid, tid, sh);    // t=1
    gbar(G0 + 3);
    ph_tb(W, &g_vT32[1][0], &g_Wc[2][0], 0, bid, tid, sh);
    gbar(G0 + 4);
    ph_s(&g_Wc[2][0], nullptr, out, bid, tid, sh);          // t=2 -> final output
}

extern "C" void kernel_launch(void* const* d_in, const int* in_sizes, int n_in,
                              void* d_out, int out_size, void* d_ws, size_t ws_size,
                              hipStream_t stream) {
    const float* x = (const float*)d_in[0];
    const float* W = (const float*)d_in[1];
    float* out = (float*)d_out;
    k_prep<<<dim3(756), dim3(256), 0, stream>>>(x, W);
    k_mega<<<dim3(NBLK), dim3(NTHR), 0, stream>>>(W, out);
}

// Round 12
// 123.911 us; speedup vs baseline: 8.5488x; 1.1728x over previous
//
#include <hip/hip_runtime.h>
#include <math.h>

// k' = c*8 + i (c-major): B-matrix [uo][k'] is W's native [c][u][o][i] layout.
// Two dispatches: k_prep, then k_mega (S0,TB0,S1,TB1,S2; 4 flag barriers).
// Versioned cross-phase buffers (Wc x3, vT x2): producers write-through
// (system-scope), consumers use plain cached loads on virgin addresses.
// NTHR=1024 (16 waves/block, 4/SIMD) for latency hiding.
#define B_ 512
#define C_ 1152
#define U_ 10
#define O_ 16
#define I_ 8
#define K_ 9216
#define UO_ 160
#define NBLK 256
#define NTHR 1024

typedef short bf16x8 __attribute__((ext_vector_type(8)));
typedef float f32x4 __attribute__((ext_vector_type(4)));
typedef unsigned short u16x8v __attribute__((ext_vector_type(8)));
typedef unsigned long long u64t;

// ---- persistent device scratch (fully overwritten every call) ----
__device__ __attribute__((aligned(16))) unsigned short g_xb2[B_*K_];     // bf16 x [b][k']
__device__ __attribute__((aligned(16))) unsigned short g_xT2[K_*B_];     // bf16 x^T [k'][b]
__device__ __attribute__((aligned(16))) unsigned short g_Wc[3][C_*1280]; // bf16 cw-scaled W, 3 versions
__device__ __attribute__((aligned(16))) unsigned g_vT32[2][UO_*B_/2];    // bf16 v^T packed u32, 2 versions
__device__ float g_b[C_*U_];           // logits (same block writes+reads its own c's)
__device__ unsigned g_gen;             // barrier generation (monotonic across replays)
__device__ unsigned g_arrive[NBLK];    // per-block arrival flags

__device__ __forceinline__ unsigned short f2bf(float f) {
    unsigned u = __builtin_bit_cast(unsigned, f);
    unsigned r = (u + 0x7FFFu + ((u >> 16) & 1u)) >> 16;
    return (unsigned short)r;
}

// write-through store (system scope): lands at coherence point, no stale L2 copies
__device__ __forceinline__ void st_sys16(unsigned short* p, u16x8v v) {
    union { u16x8v v; u64t q[2]; } u; u.v = v;
    __hip_atomic_store((u64t*)p,     u.q[0], __ATOMIC_RELAXED, __HIP_MEMORY_SCOPE_SYSTEM);
    __hip_atomic_store(((u64t*)p)+1, u.q[1], __ATOMIC_RELAXED, __HIP_MEMORY_SCOPE_SYSTEM);
}

// ---- dispatch 1: prep. x -> bf16 [b][k'] + [k'][b]; Wc[0] = bf16(0.1*W) ----
__global__ __launch_bounds__(256) void k_prep(const float* __restrict__ x,
                                              const float* __restrict__ W) {
    __shared__ unsigned short lds[32*256];
    int task = blockIdx.x, tid = threadIdx.x;
    if (task < 576) {
        int b0 = (task & 15) * 32;
        int c0 = (task >> 4) * 32;
        int li = tid >> 5, lc = tid & 31;
        for (int rep = 0; rep < 32; rep++) {
            float v = x[(b0+rep)*K_ + li*1152 + c0 + lc];
            lds[rep*256 + ((lc*8+li) ^ ((rep&31)<<3))] = f2bf(v);
        }
        __syncthreads();
        {   // xb2: 32 contiguous elems per thread
            int b = tid >> 3, part = tid & 7;
            int swz = (b&31) << 3;
            const u16x8v* lv = (const u16x8v*)lds;
            u16x8v* ov = (u16x8v*)(g_xb2 + (b0+b)*K_ + c0*8 + part*32);
            #pragma unroll
            for (int g = 0; g < 4; g++)
                ov[g] = lv[(b*256 + ((part*32 + g*8) ^ swz)) >> 3];
        }
        for (int p = 0; p < 8; p++) {   // xT2: 8 threads per k'-row
            int r = p*32 + (tid>>3);
            int bp = (tid&7)*4;
            ushort4 o;
            unsigned short* po = (unsigned short*)&o;
            #pragma unroll
            for (int q = 0; q < 4; q++) {
                int b = bp + q;
                po[q] = lds[b*256 + (r ^ ((b&31)<<3))];
            }
            *(ushort4*)(g_xT2 + (c0*8 + r)*B_ + b0 + bp) = o;
        }
    } else {
        int base = (task - 576) * 8192;
        for (int j = 0; j < 8; j++) {
            float4 v = *(const float4*)(W + base + j*1024 + tid*4);
            ushort4 o;
            o.x = f2bf(0.1f*v.x); o.y = f2bf(0.1f*v.y);
            o.z = f2bf(0.1f*v.z); o.w = f2bf(0.1f*v.w);
            *(ushort4*)(&g_Wc[0][0] + base + j*1024 + tid*4) = o;
        }
    }
}

struct TBsh { float agg[2][U_]; float cws[2][U_]; };
union ShMem {
    float red[16][16][32];        // 32 KB (S-phase cross-wave reduce)
    TBsh tb[4];                   // 4 concurrent TB task-groups
};

// ---- grid barrier: flag arrive + block-0 sweep + gen broadcast; no fences ----
__device__ __forceinline__ void gbar(unsigned target) {
    __syncthreads();                    // drains vmcnt: payload stores at coherence point
    if (threadIdx.x == 0)
        __hip_atomic_store(&g_arrive[blockIdx.x], target,
                           __ATOMIC_RELAXED, __HIP_MEMORY_SCOPE_SYSTEM);
    if (blockIdx.x == 0) {
        long spins = 0;
        for (;;) {
            int ok = 1;
            if (threadIdx.x < NBLK) {
                unsigned a = __hip_atomic_load(&g_arrive[threadIdx.x],
                                               __ATOMIC_RELAXED, __HIP_MEMORY_SCOPE_SYSTEM);
                ok = (int)(a - target) >= 0;
            }
            if (__syncthreads_count(ok) == NTHR) break;
            __builtin_amdgcn_s_sleep(4);
            if (++spins > (1L << 17)) break;        // failsafe: fail fast, never hang
        }
        if (threadIdx.x == 0)
            __hip_atomic_store(&g_gen, target, __ATOMIC_RELAXED, __HIP_MEMORY_SCOPE_SYSTEM);
    }
    if (threadIdx.x == 0) {
        long spins = 0;
        while ((int)(__hip_atomic_load(&g_gen, __ATOMIC_RELAXED, __HIP_MEMORY_SCOPE_SYSTEM) - target) < 0) {
            __builtin_amdgcn_s_sleep(8);
            if (++spins > (1L << 18)) break;        // failsafe
        }
    }
    __syncthreads();
}

// ---- phase: S = x @ Wc^T fused with squash -> vT (+ final out). 160 tasks. ----
// 16 waves split K (576 k' each, 18 MFMA iters); LDS reduce; squash by tid<256.
__device__ void ph_s(const unsigned short* __restrict__ Wcr, unsigned* vtw,
                     float* __restrict__ out, int bid, int tid, ShMem& sh) {
    if (bid < 160) {
        int lane = tid & 63, w = tid >> 6;          // w = 0..15
        int mt = bid & 31, nt = bid >> 5;
        int m0 = mt*16, n0 = nt*32;
        int ra = lane & 15;
        const unsigned short* pa  = g_xb2 + (m0+ra)*K_ + w*576 + (lane>>4)*8;
        const unsigned short* pb0 = Wcr + (w*72 + (lane>>4))*1280 + (n0+ra)*8;
        const unsigned short* pb1 = pb0 + 128;
        f32x4 acc0 = {0.f,0.f,0.f,0.f};
        f32x4 acc1 = {0.f,0.f,0.f,0.f};
        #pragma unroll 6
        for (int s = 0; s < 18; s++) {              // K/wave = 576
            bf16x8 a  = *(const bf16x8*)pa;
            bf16x8 b0 = *(const bf16x8*)pb0;
            bf16x8 b1 = *(const bf16x8*)pb1;
            acc0 = __builtin_amdgcn_mfma_f32_16x16x32_bf16(a, b0, acc0, 0, 0, 0);
            acc1 = __builtin_amdgcn_mfma_f32_16x16x32_bf16(a, b1, acc1, 0, 0, 0);
            pa += 32; pb0 += 5120; pb1 += 5120;     // +4 channels
        }
        int row = (lane>>4)*4, col = lane & 15;
        #pragma unroll
        for (int r = 0; r < 4; r++) {
            sh.red[w][row+r][col]    = acc0[r];
            sh.red[w][row+r][col+16] = acc1[r];
        }
        __syncthreads();
        if (tid < 256) {
            // squash: thread -> (b-pair bp, u, o); reduce 16 wave-partials
            int bp = tid >> 5;              // 0..7
            int u  = (tid >> 4) & 1;
            int o  = tid & 15;
            int col2 = u*16 + o;
            float t0 = 0.f, t1 = 0.f;
            #pragma unroll
            for (int ww = 0; ww < 16; ww++) {
                t0 += sh.red[ww][2*bp][col2];
                t1 += sh.red[ww][2*bp+1][col2];
            }
            float n0s = t0*t0, n1s = t1*t1;
            #pragma unroll
            for (int m = 1; m < 16; m <<= 1) {
                n0s += __shfl_xor(n0s, m);
                n1s += __shfl_xor(n1s, m);
            }
            float f0 = n0s / ((1.f + n0s) * sqrtf(n0s));
            float f1 = n1s / ((1.f + n1s) * sqrtf(n1s));
            float v0 = t0*f0, v1 = t1*f1;
            int ug = nt*2 + u;
            int bg = m0 + 2*bp;
            if (vtw) {
                unsigned pack = (unsigned)f2bf(v0) | ((unsigned)f2bf(v1) << 16);
                __hip_atomic_store(&vtw[((ug*16+o)*B_ + bg) >> 1], pack,
                                   __ATOMIC_RELAXED, __HIP_MEMORY_SCOPE_SYSTEM);
            } else {
                out[(bg*10 + ug)*16 + o]       = v0;
                out[((bg+1)*10 + ug)*16 + o]   = v1;
            }
        }
        __syncthreads();                        // sh.red safe before next phase
    }
}

// ---- phase: TB. 4 groups x 4 waves; group g runs task bid+256g. 576 tasks. ----
__device__ void ph_tb(const float* __restrict__ W, const unsigned* vtr,
                      unsigned short* Wcw, int first, int bid, int tid, ShMem& sh) {
    int lane = tid & 63, lw = (tid >> 6) & 3, g = tid >> 8;
    int ltid = tid & 255;
    int t = bid + 256*g;
    int valid = (t < 576);
    const unsigned short* vT = (const unsigned short*)vtr;
    int c0 = t * 2;
    int ra = lane & 15, kq = (lane>>4)*8;
    int ct = lane >> 5;
    int i0 = ((lane>>4) & 1) * 4;
    int o  = lane & 15;
    if (valid) {
        const unsigned short* pa0 = g_xT2 + (c0*8 + ra)*B_ + kq;
        for (int nt = lw; nt < 5; nt += 4) {    // wave lw=0 also covers tile 4
            int n0 = nt*32;
            const unsigned short* pa  = pa0;
            const unsigned short* pb0 = vT + (n0+ra)*B_ + kq;
            const unsigned short* pb1 = pb0 + 16*B_;
            f32x4 acc0 = {0.f,0.f,0.f,0.f};
            f32x4 acc1 = {0.f,0.f,0.f,0.f};
            #pragma unroll 4
            for (int s = 0; s < 16; s++) {      // K = 512
                bf16x8 a  = *(const bf16x8*)pa;
                bf16x8 b0 = *(const bf16x8*)pb0;
                bf16x8 b1 = *(const bf16x8*)pb1;
                acc0 = __builtin_amdgcn_mfma_f32_16x16x32_bf16(a, b0, acc0, 0, 0, 0);
                acc1 = __builtin_amdgcn_mfma_f32_16x16x32_bf16(a, b1, acc1, 0, 0, 0);
                pa += 32; pb0 += 32; pb1 += 32;
            }
            const float* wr = W + (c0+ct)*1280;
            float4 wa = *(const float4*)(wr + (2*nt  )*128 + o*8 + i0);
            float4 wb = *(const float4*)(wr + (2*nt+1)*128 + o*8 + i0);
            float p0 = wa.x*acc0[0] + wa.y*acc0[1] + wa.z*acc0[2] + wa.w*acc0[3];
            float p1 = wb.x*acc1[0] + wb.y*acc1[1] + wb.z*acc1[2] + wb.w*acc1[3];
            #pragma unroll
            for (int m = 1; m < 32; m <<= 1) {
                p0 += __shfl_xor(p0, m);
                p1 += __shfl_xor(p1, m);
            }
            if ((lane & 31) == 0) {
                sh.tb[g].agg[ct][2*nt]   = p0 * (1.f/512.f);
                sh.tb[g].agg[ct][2*nt+1] = p1 * (1.f/512.f);
            }
        }
    }
    __syncthreads();
    if (valid && ltid < 2) {                    // per-channel b-update + softmax
        int c = c0 + ltid;
        float bv[U_];
        float mx = -3e38f;
        #pragma unroll
        for (int u = 0; u < U_; u++) {
            float v = sh.tb[g].agg[ltid][u];
            if (!first) v += g_b[c*U_ + u];
            g_b[c*U_ + u] = v;
            bv[u] = v;
            mx = fmaxf(mx, v);
        }
        float sm = 0.f;
        #pragma unroll
        for (int u = 0; u < U_; u++) { bv[u] = expf(bv[u] - mx); sm += bv[u]; }
        float inv = 1.f/sm;
        #pragma unroll
        for (int u = 0; u < U_; u++) sh.tb[g].cws[ltid][u] = bv[u]*inv;
    }
    __syncthreads();
    if (valid) {
        for (int e = ltid*8; e < 2560; e += 2048) {   // next-iter Wc, write-through
            int ch  = (e >= 1280) ? 1 : 0;
            int off = e - ch*1280;
            int u   = off >> 7;
            float s = sh.tb[g].cws[ch][u];
            const float* wp = W + (c0+ch)*1280 + off;
            float4 a4 = *(const float4*)wp;
            float4 b4 = *(const float4*)(wp + 4);
            u16x8v ov;
            ov[0] = f2bf(a4.x*s); ov[1] = f2bf(a4.y*s); ov[2] = f2bf(a4.z*s); ov[3] = f2bf(a4.w*s);
            ov[4] = f2bf(b4.x*s); ov[5] = f2bf(b4.y*s); ov[6] = f2bf(b4.z*s); ov[7] = f2bf(b4.w*s);
            st_sys16(Wcw + (c0+ch)*1280 + off, ov);
        }
    }
    __syncthreads();                            // sh.tb safe before next phase
}

// ---- dispatch 2: persistent kernel, 5 phases, 4 flag barriers ----
__global__ __launch_bounds__(NTHR) void k_mega(const float* __restrict__ W,
                                               float* __restrict__ out) {
    __shared__ ShMem sh;
    __shared__ unsigned sG0;
    int bid = blockIdx.x, tid = threadIdx.x;
    if (tid == 0)
        sG0 = __hip_atomic_load(&g_gen, __ATOMIC_RELAXED, __HIP_MEMORY_SCOPE_SYSTEM);
    __syncthreads();
    unsigned G0 = sG0;
    ph_s(&g_Wc[0][0], &g_vT32[0][0], out, bid, tid, sh);    // t=0
    gbar(G0 + 1);
    ph_tb(W, &g_vT32[0][0], &g_Wc[1][0], 1, bid, tid, sh);
    gbar(G0 + 2);
    ph_s(&g_Wc[1][0], &g_vT32[1][0], out, bid, tid, sh);    // t=1
    gbar(G0 + 3);
    ph_tb(W, &g_vT32[1][0], &g_Wc[2][0], 0, bid, tid, sh);
    gbar(G0 + 4);
    ph_s(&g_Wc[2][0], nullptr, out, bid, tid, sh);          // t=2 -> final output
}

extern "C" void kernel_launch(void* const* d_in, const int* in_sizes, int n_in,
                              void* d_out, int out_size, void* d_ws, size_t ws_size,
                              hipStream_t stream) {
    const float* x = (const float*)d_in[0];
    const float* W = (const float*)d_in[1];
    float* out = (float*)d_out;
    k_prep<<<dim3(756), dim3(256), 0, stream>>>(x, W);
    k_mega<<<dim3(NBLK), dim3(NTHR), 0, stream>>>(W, out);
}